// Round 2
// baseline (671.078 us; speedup 1.0000x reference)
//
#include <hip/hip_runtime.h>

#define NTOK 4096     // H*W
#define CDIM 64
#define HID  128
#define NEGS 0.01f
#define EPSV 1e-5f

// workspace layout in floats
#define OFF_W2T 0                       // 5 * 8192 transposed w2 matrices
#define OFF_QA  65536                   // [B,C,N] = 524288 floats each
#define OFF_KA  (OFF_QA + 524288)
#define OFF_VA  (OFF_KA + 524288)
#define OFF_XA  (OFF_VA + 524288)

typedef __attribute__((address_space(1))) const void GV;
typedef __attribute__((address_space(3))) void LV;

__device__ __forceinline__ void gll16(const float* g, float* l) {
    __builtin_amdgcn_global_load_lds((GV*)g, (LV*)l, 16, 0, 0);
}

// ---------------------------------------------------------------- K0: transpose the five w2 [64][128] -> w2t [128][64]
__global__ __launch_bounds__(256) void k0_transpose_w2(
    const float* __restrict__ s0, const float* __restrict__ s1,
    const float* __restrict__ s2, const float* __restrict__ s3,
    const float* __restrict__ s4, float* __restrict__ w2t)
{
    int wsel = blockIdx.x;
    const float* src = wsel == 0 ? s0 : wsel == 1 ? s1 : wsel == 2 ? s2 : wsel == 3 ? s3 : s4;
    float* dst = w2t + wsel * 8192;
    int t = threadIdx.x;
    for (int p = 0; p < 32; ++p) {
        int e = t + p * 256;            // 0..8191
        int o = e >> 7, j = e & 127;
        dst[j * 64 + o] = src[e];
    }
}

// ---------------------------------------------------------------- shared MLP partial (4-way j-split + butterfly merge)
__device__ __forceinline__ void mlp_partial(const float* __restrict__ x, float* __restrict__ acc,
                                            const float* __restrict__ w1, const float* __restrict__ b1,
                                            const float* __restrict__ w2t, int sub)
{
#pragma unroll
    for (int o = 0; o < 64; ++o) acc[o] = 0.f;
    int j0 = sub << 5;
#pragma unroll 2
    for (int jj = 0; jj < 32; ++jj) {
        int j = j0 + jj;
        const float4* w1r = (const float4*)(w1 + (j << 6));
        float h0 = 0.f, h1 = 0.f, h2 = 0.f, h3 = 0.f;
#pragma unroll
        for (int cc = 0; cc < 16; ++cc) {
            float4 wv = w1r[cc];
            h0 += x[4 * cc + 0] * wv.x; h1 += x[4 * cc + 1] * wv.y;
            h2 += x[4 * cc + 2] * wv.z; h3 += x[4 * cc + 3] * wv.w;
        }
        float hh = (h0 + h1) + (h2 + h3) + b1[j];
        hh = hh > 0.f ? hh : NEGS * hh;
        const float4* w2r = (const float4*)(w2t + (j << 6));
#pragma unroll
        for (int cc = 0; cc < 16; ++cc) {
            float4 wv = w2r[cc];
            acc[4 * cc + 0] += hh * wv.x; acc[4 * cc + 1] += hh * wv.y;
            acc[4 * cc + 2] += hh * wv.z; acc[4 * cc + 3] += hh * wv.w;
        }
    }
    // merge the 4 j-partials: lanes (tl, tl+16, tl+32, tl+48) hold the same token
#pragma unroll
    for (int o = 0; o < 64; ++o) {
        float a = acc[o];
        a += __shfl_xor(a, 16);
        a += __shfl_xor(a, 32);
        acc[o] = a;
    }
}

// ---------------------------------------------------------------- K1: LayerNorm + MLP for q/k/v  (in,out: [B,C,N])
struct K1Args {
    const float *x, *g, *b, *w1, *b1, *w2t, *b2;
    float* o;
};

__global__ __launch_bounds__(256) void k1_ln_mlp(K1Args a0, K1Args a1, K1Args a2)
{
    const K1Args& a = blockIdx.y == 0 ? a0 : blockIdx.y == 1 ? a1 : a2;
    int t = threadIdx.x;
    int lane = t & 63, wave = t >> 6;
    int sub = lane >> 4, tl = lane & 15;
    int tok = blockIdx.x * 64 + wave * 16 + tl;
    int b = tok >> 12, n = tok & 4095;
    const float* xp = a.x + (size_t)b * (CDIM * NTOK) + n;
    float x[64];
#pragma unroll
    for (int c = 0; c < 64; ++c) x[c] = xp[(size_t)c * NTOK];
    // LayerNorm over C
    float s0 = 0.f, s1 = 0.f, s2 = 0.f, s3 = 0.f;
#pragma unroll
    for (int c = 0; c < 64; c += 4) { s0 += x[c]; s1 += x[c + 1]; s2 += x[c + 2]; s3 += x[c + 3]; }
    float mean = ((s0 + s1) + (s2 + s3)) * (1.f / 64.f);
    float v0 = 0.f, v1 = 0.f, v2 = 0.f, v3 = 0.f;
#pragma unroll
    for (int c = 0; c < 64; c += 4) {
        float d0 = x[c] - mean, d1 = x[c + 1] - mean, d2 = x[c + 2] - mean, d3 = x[c + 3] - mean;
        v0 += d0 * d0; v1 += d1 * d1; v2 += d2 * d2; v3 += d3 * d3;
    }
    float rstd = rsqrtf(((v0 + v1) + (v2 + v3)) * (1.f / 64.f) + EPSV);
#pragma unroll
    for (int c = 0; c < 64; ++c) x[c] = (x[c] - mean) * rstd * a.g[c] + a.b[c];

    float acc[64];
    mlp_partial(x, acc, a.w1, a.b1, a.w2t, sub);

    if (sub == 0) {
        float* op = a.o + (size_t)b * (CDIM * NTOK) + n;
#pragma unroll
        for (int o = 0; o < 64; ++o) op[(size_t)o * NTOK] = acc[o] + a.b2[o];
    }
}

// ---------------------------------------------------------------- K2: dense attention, flash-style, fp32
// qa/ka/va: [B,C,N] where channel c = h*16+d  => per-head [d][n]
// Double-buffered async staging via global_load_lds; 1 raw barrier per tile.
__global__ __launch_bounds__(256) void k2_attn(
    const float* __restrict__ qa, const float* __restrict__ ka,
    const float* __restrict__ va, float* __restrict__ xa)
{
    __shared__ float SM[2][4][2][16][64];   // 64 KB: [buf][kj-quarter][K/V][d][j]
    int t = threadIdx.x;
    int r = t & 63;         // q-row within tile
    int qq = t >> 6;        // wave index == kj quarter
    int bh = blockIdx.y;
    int b = bh >> 2, h = bh & 3;
    int qbase = blockIdx.x << 6;
    size_t hb = (size_t)b * (CDIM * NTOK) + (size_t)(h * 16) * NTOK;
    const float* qh = qa + hb;
    const float* kh = ka + hb;
    const float* vh = va + hb;
    float* lbase = &SM[0][0][0][0][0];

    // loop-invariant per-lane staging sources: e4 = t + p*256 decodes to
    // [tq][wv][d][g]; quarter tq consumes ktile tq*16+it at iteration it.
    const float* gsrc[8];
#pragma unroll
    for (int p = 0; p < 8; ++p) {
        int e4 = t + (p << 8);
        int tq = e4 >> 9, rem = e4 & 511, wv = rem >> 8, r2 = rem & 255;
        int d = r2 >> 4, g = r2 & 15;
        gsrc[p] = (wv ? vh : kh) + (size_t)d * NTOK + (tq << 10) + (g << 2);
    }

    float qreg[16];
#pragma unroll
    for (int d = 0; d < 16; ++d) qreg[d] = qh[(size_t)d * NTOK + qbase + r] * 0.25f; // fold 1/sqrt(16)
    float m = -1e30f, l = 0.f;
    float acc[16];
#pragma unroll
    for (int d = 0; d < 16; ++d) acc[d] = 0.f;

    // prologue: stage tile 0 into buf 0 (LDS dest = uniform base + lane*16: OK)
#pragma unroll
    for (int p = 0; p < 8; ++p) gll16(gsrc[p], lbase + ((t + (p << 8)) << 2));

#pragma unroll 1
    for (int it = 0; it < 16; ++it) {
        int cb = it & 1;
        asm volatile("s_waitcnt vmcnt(0)" ::: "memory");   // own tile-it loads done
        __builtin_amdgcn_s_barrier();                      // => everyone's are done
        asm volatile("" ::: "memory");
        if (it < 15) {                                     // prefetch tile it+1
            float* nb = lbase + ((cb ^ 1) << 13);
#pragma unroll
            for (int p = 0; p < 8; ++p)
                gll16(gsrc[p] + ((it + 1) << 6), nb + ((t + (p << 8)) << 2));
        }
        const float4* Kq = (const float4*)&SM[cb][qq][0][0][0];
        const float4* Vq = (const float4*)&SM[cb][qq][1][0][0];
        float s[64];
        {   // d = 0 initializes
            float q0 = qreg[0];
#pragma unroll
            for (int g = 0; g < 16; ++g) {
                float4 kv = Kq[g];
                s[4 * g + 0] = q0 * kv.x; s[4 * g + 1] = q0 * kv.y;
                s[4 * g + 2] = q0 * kv.z; s[4 * g + 3] = q0 * kv.w;
            }
        }
#pragma unroll
        for (int d = 1; d < 16; ++d) {
            float qd = qreg[d];
#pragma unroll
            for (int g = 0; g < 16; ++g) {
                float4 kv = Kq[d * 16 + g];
                s[4 * g + 0] += qd * kv.x; s[4 * g + 1] += qd * kv.y;
                s[4 * g + 2] += qd * kv.z; s[4 * g + 3] += qd * kv.w;
            }
        }
        float mx = s[0];
#pragma unroll
        for (int i2 = 1; i2 < 64; ++i2) mx = fmaxf(mx, s[i2]);
        float mnew = fmaxf(m, mx);
        float corr = __expf(m - mnew);
        l *= corr;
#pragma unroll
        for (int d = 0; d < 16; ++d) acc[d] *= corr;
        float ls0 = 0.f, ls1 = 0.f, ls2 = 0.f, ls3 = 0.f;
#pragma unroll
        for (int i2 = 0; i2 < 64; i2 += 4) {
            s[i2 + 0] = __expf(s[i2 + 0] - mnew); ls0 += s[i2 + 0];
            s[i2 + 1] = __expf(s[i2 + 1] - mnew); ls1 += s[i2 + 1];
            s[i2 + 2] = __expf(s[i2 + 2] - mnew); ls2 += s[i2 + 2];
            s[i2 + 3] = __expf(s[i2 + 3] - mnew); ls3 += s[i2 + 3];
        }
        l += (ls0 + ls1) + (ls2 + ls3);
#pragma unroll
        for (int d = 0; d < 16; ++d) {
            float a0 = 0.f, a1 = 0.f, a2 = 0.f, a3 = 0.f;
#pragma unroll
            for (int g = 0; g < 16; ++g) {
                float4 vv = Vq[d * 16 + g];
                a0 += s[4 * g + 0] * vv.x; a1 += s[4 * g + 1] * vv.y;
                a2 += s[4 * g + 2] * vv.z; a3 += s[4 * g + 3] * vv.w;
            }
            acc[d] += (a0 + a1) + (a2 + a3);
        }
        m = mnew;
    }

    // merge the 4 kj-quarters; scratch aliases SM[0] (dead: last compute read SM[1])
    float (*part)[64][18] = (float (*)[64][18])lbase;   // [4][64][18] = 4608 floats
    part[qq][r][0] = m;
    part[qq][r][1] = l;
#pragma unroll
    for (int d = 0; d < 16; ++d) part[qq][r][2 + d] = acc[d];
    __syncthreads();
    if (t < 64) {
        float m0 = part[0][t][0], m1v = part[1][t][0], m2v = part[2][t][0], m3v = part[3][t][0];
        float M = fmaxf(fmaxf(m0, m1v), fmaxf(m2v, m3v));
        float e0 = __expf(m0 - M), e1 = __expf(m1v - M), e2 = __expf(m2v - M), e3 = __expf(m3v - M);
        float L = part[0][t][1] * e0 + part[1][t][1] * e1 + part[2][t][1] * e2 + part[3][t][1] * e3;
        float rL = 1.f / L;
        float* op = xa + hb + qbase + t;
#pragma unroll
        for (int d = 0; d < 16; ++d) {
            float o = part[0][t][2 + d] * e0 + part[1][t][2 + d] * e1 +
                      part[2][t][2 + d] * e2 + part[3][t][2 + d] * e3;
            op[(size_t)d * NTOK] = o * rL;
        }
    }
}

// ---------------------------------------------------------------- K3: rs1 = va + mlp1(xattn); rs2 = rs1 + mlp2(rs1)
__global__ __launch_bounds__(256) void k3_res_mlp(
    const float* __restrict__ xa, const float* __restrict__ va,
    const float* __restrict__ w1a, const float* __restrict__ b1a,
    const float* __restrict__ w2ta, const float* __restrict__ b2a,
    const float* __restrict__ w1b, const float* __restrict__ b1b,
    const float* __restrict__ w2tb, const float* __restrict__ b2b,
    float* __restrict__ outp)
{
    int t = threadIdx.x;
    int lane = t & 63, wave = t >> 6;
    int sub = lane >> 4, tl = lane & 15;
    int tok = blockIdx.x * 64 + wave * 16 + tl;
    int b = tok >> 12, n = tok & 4095;
    const float* xp = xa + (size_t)b * (CDIM * NTOK) + n;
    const float* vp = va + (size_t)b * (CDIM * NTOK) + n;
    float x[64];
#pragma unroll
    for (int c = 0; c < 64; ++c) x[c] = xp[(size_t)c * NTOK];

    float acc[64];
    mlp_partial(x, acc, w1a, b1a, w2ta, sub);
    // rs1 (identical in all 4 sub-lanes after butterfly merge)
#pragma unroll
    for (int c = 0; c < 64; ++c) x[c] = vp[(size_t)c * NTOK] + acc[c] + b2a[c];

    mlp_partial(x, acc, w1b, b1b, w2tb, sub);

    if (sub == 0) {
        float* op = outp + (size_t)b * (CDIM * NTOK) + n;
#pragma unroll
        for (int o = 0; o < 64; ++o) op[(size_t)o * NTOK] = x[o] + acc[o] + b2b[o];
    }
}

// ----------------------------------------------------------------
extern "C" void kernel_launch(void* const* d_in, const int* in_sizes, int n_in,
                              void* d_out, int out_size, void* d_ws, size_t ws_size,
                              hipStream_t stream)
{
    (void)in_sizes; (void)n_in; (void)out_size; (void)ws_size;
    const float* q = (const float*)d_in[0];
    const float* k = (const float*)d_in[1];
    const float* v = (const float*)d_in[2];
    const float* q_ln_g = (const float*)d_in[3];
    const float* q_ln_b = (const float*)d_in[4];
    const float* q_w1 = (const float*)d_in[5];
    const float* q_b1 = (const float*)d_in[6];
    const float* q_w2 = (const float*)d_in[7];
    const float* q_b2 = (const float*)d_in[8];
    const float* k_ln_g = (const float*)d_in[9];
    const float* k_ln_b = (const float*)d_in[10];
    const float* k_w1 = (const float*)d_in[11];
    const float* k_b1 = (const float*)d_in[12];
    const float* k_w2 = (const float*)d_in[13];
    const float* k_b2 = (const float*)d_in[14];
    const float* v_ln_g = (const float*)d_in[15];
    const float* v_ln_b = (const float*)d_in[16];
    const float* v_w1 = (const float*)d_in[17];
    const float* v_b1 = (const float*)d_in[18];
    const float* v_w2 = (const float*)d_in[19];
    const float* v_b2 = (const float*)d_in[20];
    const float* m1_w1 = (const float*)d_in[21];
    const float* m1_b1 = (const float*)d_in[22];
    const float* m1_w2 = (const float*)d_in[23];
    const float* m1_b2 = (const float*)d_in[24];
    const float* m2_w1 = (const float*)d_in[25];
    const float* m2_b1 = (const float*)d_in[26];
    const float* m2_w2 = (const float*)d_in[27];
    const float* m2_b2 = (const float*)d_in[28];

    float* ws  = (float*)d_ws;
    float* w2t = ws + OFF_W2T;
    float* qa  = ws + OFF_QA;
    float* ka  = ws + OFF_KA;
    float* va  = ws + OFF_VA;
    float* xa  = ws + OFF_XA;
    float* out = (float*)d_out;

    k0_transpose_w2<<<5, 256, 0, stream>>>(q_w2, k_w2, v_w2, m1_w2, m2_w2, w2t);

    K1Args aq = { q, q_ln_g, q_ln_b, q_w1, q_b1, w2t + 0 * 8192, q_b2, qa };
    K1Args ak = { k, k_ln_g, k_ln_b, k_w1, k_b1, w2t + 1 * 8192, k_b2, ka };
    K1Args av = { v, v_ln_g, v_ln_b, v_w1, v_b1, w2t + 2 * 8192, v_b2, va };
    k1_ln_mlp<<<dim3(128, 3), 256, 0, stream>>>(aq, ak, av);

    k2_attn<<<dim3(64, 8), 256, 0, stream>>>(qa, ka, va, xa);

    k3_res_mlp<<<128, 256, 0, stream>>>(xa, va, m1_w1, m1_b1, w2t + 3 * 8192, m1_b2,
                                        m2_w1, m2_b1, w2t + 4 * 8192, m2_b2, out);
}

// Round 9
// 420.652 us; speedup vs baseline: 1.5953x; 1.5953x over previous
//
#include <hip/hip_runtime.h>

#define NTOK 4096     // H*W
#define NEGS 0.01f
#define EPSV 1e-5f

typedef unsigned short u16t;
typedef unsigned int u32t;

// workspace layout in float units
#define OFF_W2T 0                        // 5*8192 transposed w2
#define OFF_VA  65536                    // fp32 [B,C,N]
#define OFF_XA  (OFF_VA + 524288)        // fp32 [B,C,N]
#define OFF_QBF (OFF_XA + 524288)        // 524288 u16 = 262144 f  [bh][n][16] (scaled)
#define OFF_KBF (OFF_QBF + 262144)       // [bh][n][16]
#define OFF_VTB (OFF_KBF + 262144)       // [b][c][n] bf16 transposed V

typedef __attribute__((address_space(1))) const void GV;
typedef __attribute__((address_space(3))) void LV;
using bf16x8 = __attribute__((ext_vector_type(8))) short;
using f32x4  = __attribute__((ext_vector_type(4))) float;

__device__ __forceinline__ void gll16(const void* g, void* l) {
    __builtin_amdgcn_global_load_lds((GV*)g, (LV*)l, 16, 0, 0);
}
// round-to-nearest-even f32 -> bf16 (raw bits; no hip_bf16 header types)
__device__ __forceinline__ u32t bf16r(float x) {
    u32t u = __builtin_bit_cast(u32t, x);
    return (u + 0x7fffu + ((u >> 16) & 1u)) >> 16;
}
__device__ __forceinline__ u32t pk2(float a, float b) {
    return bf16r(a) | (bf16r(b) << 16);
}

// ---------------------------------------------------------------- K0: transpose five w2 [64][128] -> [128][64]
__global__ __launch_bounds__(256) void k0_transpose_w2(
    const float* __restrict__ s0, const float* __restrict__ s1,
    const float* __restrict__ s2, const float* __restrict__ s3,
    const float* __restrict__ s4, float* __restrict__ w2t)
{
    int wsel = blockIdx.x;
    const float* src = wsel == 0 ? s0 : wsel == 1 ? s1 : wsel == 2 ? s2 : wsel == 3 ? s3 : s4;
    float* dst = w2t + wsel * 8192;
    int t = threadIdx.x;
    for (int p = 0; p < 32; ++p) {
        int e = t + p * 256;
        int o = e >> 7, j = e & 127;
        dst[j * 64 + o] = src[e];
    }
}

// ---------------------------------------------------------------- shared MLP partial (4-way j-split + butterfly merge)
__device__ __forceinline__ void mlp_partial(const float* __restrict__ x, float* __restrict__ acc,
                                            const float* __restrict__ w1, const float* __restrict__ b1,
                                            const float* __restrict__ w2t, int sub)
{
#pragma unroll
    for (int o = 0; o < 64; ++o) acc[o] = 0.f;
    int j0 = sub << 5;
#pragma unroll 2
    for (int jj = 0; jj < 32; ++jj) {
        int j = j0 + jj;
        const float4* w1r = (const float4*)(w1 + (j << 6));
        float h0 = 0.f, h1 = 0.f, h2 = 0.f, h3 = 0.f;
#pragma unroll
        for (int cc = 0; cc < 16; ++cc) {
            float4 wv = w1r[cc];
            h0 += x[4 * cc + 0] * wv.x; h1 += x[4 * cc + 1] * wv.y;
            h2 += x[4 * cc + 2] * wv.z; h3 += x[4 * cc + 3] * wv.w;
        }
        float hh = (h0 + h1) + (h2 + h3) + b1[j];
        hh = hh > 0.f ? hh : NEGS * hh;
        const float4* w2r = (const float4*)(w2t + (j << 6));
#pragma unroll
        for (int cc = 0; cc < 16; ++cc) {
            float4 wv = w2r[cc];
            acc[4 * cc + 0] += hh * wv.x; acc[4 * cc + 1] += hh * wv.y;
            acc[4 * cc + 2] += hh * wv.z; acc[4 * cc + 3] += hh * wv.w;
        }
    }
#pragma unroll
    for (int o = 0; o < 64; ++o) {
        float a = acc[o];
        a += __shfl_xor(a, 16);
        a += __shfl_xor(a, 32);
        acc[o] = a;
    }
}

// ---------------------------------------------------------------- K1: LayerNorm + MLP, emits attention-ready bf16 layouts
struct K1Args {
    const float *x, *g, *b, *w1, *b1, *w2t, *b2;
    float* ofp;      // fp32 [B,C,N] (v only)
    u16t* obf;       // bf16 out
    int mode;        // 0: obf=[bh][n][16] rows; 1: ofp fp32 + obf=[b][c][n]
    float scale;     // folded into bf16 values
};

__global__ __launch_bounds__(256) void k1_ln_mlp(K1Args a0, K1Args a1, K1Args a2)
{
    const K1Args& a = blockIdx.y == 0 ? a0 : blockIdx.y == 1 ? a1 : a2;
    int t = threadIdx.x;
    int lane = t & 63, wave = t >> 6;
    int sub = lane >> 4, tl = lane & 15;
    int tok = blockIdx.x * 64 + wave * 16 + tl;
    int b = tok >> 12, n = tok & 4095;
    const float* xp = a.x + (size_t)b * (64 * NTOK) + n;
    float x[64];
#pragma unroll
    for (int c = 0; c < 64; ++c) x[c] = xp[(size_t)c * NTOK];
    float s0 = 0.f, s1 = 0.f, s2 = 0.f, s3 = 0.f;
#pragma unroll
    for (int c = 0; c < 64; c += 4) { s0 += x[c]; s1 += x[c + 1]; s2 += x[c + 2]; s3 += x[c + 3]; }
    float mean = ((s0 + s1) + (s2 + s3)) * (1.f / 64.f);
    float v0 = 0.f, v1 = 0.f, v2 = 0.f, v3 = 0.f;
#pragma unroll
    for (int c = 0; c < 64; c += 4) {
        float d0 = x[c] - mean, d1 = x[c + 1] - mean, d2 = x[c + 2] - mean, d3 = x[c + 3] - mean;
        v0 += d0 * d0; v1 += d1 * d1; v2 += d2 * d2; v3 += d3 * d3;
    }
    float rstd = rsqrtf(((v0 + v1) + (v2 + v3)) * (1.f / 64.f) + EPSV);
#pragma unroll
    for (int c = 0; c < 64; ++c) x[c] = (x[c] - mean) * rstd * a.g[c] + a.b[c];

    float acc[64];
    mlp_partial(x, acc, a.w1, a.b1, a.w2t, sub);

    if (sub == 0) {
        if (a.mode == 0) {
            // bf16 rows [bh = b*4+h][n][16], value scaled
#pragma unroll
            for (int h = 0; h < 4; ++h) {
                u32t u[8];
#pragma unroll
                for (int e = 0; e < 8; ++e) {
                    float ya = (acc[h * 16 + 2 * e] + a.b2[h * 16 + 2 * e]) * a.scale;
                    float yb = (acc[h * 16 + 2 * e + 1] + a.b2[h * 16 + 2 * e + 1]) * a.scale;
                    u[e] = pk2(ya, yb);
                }
                u16t* base = a.obf + (((size_t)b * 4 + h) * NTOK + n) * 16;
                uint4* b4 = (uint4*)base;
                b4[0] = make_uint4(u[0], u[1], u[2], u[3]);
                b4[1] = make_uint4(u[4], u[5], u[6], u[7]);
            }
        } else {
            float* op = a.ofp + (size_t)b * (64 * NTOK) + n;
            u16t* vb = a.obf + (size_t)b * (64 * NTOK) + n;
#pragma unroll
            for (int c = 0; c < 64; ++c) {
                float y = acc[c] + a.b2[c];
                op[(size_t)c * NTOK] = y;
                vb[(size_t)c * NTOK] = (u16t)bf16r(y);
            }
        }
    }
}

// ---------------------------------------------------------------- K2: MFMA flash attention
// qbf/kbf: [bh][n][16] bf16 rows (Q pre-scaled by 0.25*log2e); vtb: [b][c][n] bf16.
// Per block: 64 q-rows (4 waves x 16), full j sweep in 64-wide tiles, double-buffered
// global_load_lds staging with pre-swizzled global sources.
__global__ __launch_bounds__(256) void k2_attn(
    const u16t* __restrict__ qbf, const u16t* __restrict__ kbf,
    const u16t* __restrict__ vtb, float* __restrict__ xa)
{
    // [0,8192): K/V tiles, 2 buffers x (K 2KB + V 2KB); [8192,+4*2304): per-wave P bounce
    __shared__ __align__(16) char sm[8192 + 4 * 2304];
    int t = threadIdx.x;
    int l = t & 63, w = t >> 6;
    int q = l & 15, gq = l >> 4;
    int bh = blockIdx.y;
    int b = bh >> 2, h = bh & 3;
    int qb0 = blockIdx.x * 64 + w * 16;

    const u16t* qhead = qbf + (size_t)bh * NTOK * 16;
    const u16t* khead = kbf + (size_t)bh * NTOK * 16;
    const char* vhead = (const char*)(vtb + ((size_t)b * 64 + h * 16) * NTOK);
    float* xh = xa + ((size_t)b * 64 + h * 16) * NTOK;

    // Q B-frag (loop-invariant): lane holds Q[q=l&15][d=(l>>4)*8+i]; d>=16 -> 0
    bf16x8 qf = {};
    if (l < 32) {
        uint4 u = *(const uint4*)(qhead + ((size_t)(qb0 + q)) * 16 + gq * 8);
        qf = __builtin_bit_cast(bf16x8, u);
    }

    // staging: waves 0,1 -> K tile (64 rows x 32B, XOR half-swap on j bit2);
    //          waves 2,3 -> V tile (16 rows x 128B, XOR (d&7)<<4 within row)
    const char* gsrc;
    int gstep;
    char* ldst;
    if (w < 2) {
        int s = w * 64 + l;                 // 0..127 over 2KB
        int j = s >> 1, half = s & 1;
        int xh2 = half ^ ((j >> 2) & 1);
        gsrc = (const char*)khead + j * 32 + xh2 * 16;
        gstep = 2048;
        ldst = sm + w * 1024;
    } else {
        int s = (w - 2) * 64 + l;
        int d = s >> 3, su = s & 7;
        gsrc = vhead + d * 8192 + ((su * 16) ^ ((d & 7) << 4));
        gstep = 128;
        ldst = sm + 2048 + (w - 2) * 1024;
    }
    char* pb = sm + 8192 + w * 2304;

    // precomputed LDS byte offsets
    int ka_off = q * 32 + (((gq & 1) ^ ((l >> 2) & 1)) << 4);          // + tj*512 (lanes<32)
    int va_off0 = q * 128 + (((gq << 4) + 0) ^ ((q & 7) << 4));        // chunk 0
    int va_off1 = q * 128 + (((gq << 4) + 64) ^ ((q & 7) << 4));       // chunk 1
    int pw_off = q * 144 + (gq << 3);                                  // + tj*32
    int pr_off0 = q * 144 + (gq << 4);
    int pr_off1 = q * 144 + 64 + (gq << 4);

    f32x4 acc = {0.f, 0.f, 0.f, 0.f};
    float m = -1e30f, lsum = 0.f;

    gll16(gsrc, ldst);                       // prologue: tile 0 -> buf 0

    int cur = 0;
#pragma unroll 1
    for (int it = 0; it < 64; ++it) {
        asm volatile("s_waitcnt vmcnt(0)" ::: "memory");
        __builtin_amdgcn_s_barrier();
        asm volatile("" ::: "memory");
        if (it < 63) gll16(gsrc + (it + 1) * gstep, ldst + ((cur ^ 1) << 12));
        const char* kb = sm + (cur << 12);
        const char* vb = kb + 2048;

        // QK^T (swapped): sf[tj] = mfma(A=K-frag, B=Q-frag) -> lane holds S'[j][q],
        // j = tj*16 + 4*gq + i, q = l&15, scores already in log2 domain
        f32x4 z = {0.f, 0.f, 0.f, 0.f};
        f32x4 sf0, sf1, sf2, sf3;
        {
            bf16x8 k0 = {}, k1 = {}, k2v = {}, k3v = {};
            if (l < 32) {
                k0  = __builtin_bit_cast(bf16x8, *(const uint4*)(kb + 0 * 512 + ka_off));
                k1  = __builtin_bit_cast(bf16x8, *(const uint4*)(kb + 1 * 512 + ka_off));
                k2v = __builtin_bit_cast(bf16x8, *(const uint4*)(kb + 2 * 512 + ka_off));
                k3v = __builtin_bit_cast(bf16x8, *(const uint4*)(kb + 3 * 512 + ka_off));
            }
            sf0 = __builtin_amdgcn_mfma_f32_16x16x32_bf16(k0,  qf, z, 0, 0, 0);
            sf1 = __builtin_amdgcn_mfma_f32_16x16x32_bf16(k1,  qf, z, 0, 0, 0);
            sf2 = __builtin_amdgcn_mfma_f32_16x16x32_bf16(k2v, qf, z, 0, 0, 0);
            sf3 = __builtin_amdgcn_mfma_f32_16x16x32_bf16(k3v, qf, z, 0, 0, 0);
        }
        float p[16];
#pragma unroll
        for (int i = 0; i < 4; ++i) {
            p[i] = sf0[i]; p[4 + i] = sf1[i]; p[8 + i] = sf2[i]; p[12 + i] = sf3[i];
        }
        float mx = p[0];
#pragma unroll
        for (int i = 1; i < 16; ++i) mx = fmaxf(mx, p[i]);
        mx = fmaxf(mx, __shfl_xor(mx, 16));
        mx = fmaxf(mx, __shfl_xor(mx, 32));
        float mnew = fmaxf(m, mx);
        float corr = exp2f(m - mnew);
        float ls = 0.f;
#pragma unroll
        for (int i = 0; i < 16; ++i) { p[i] = exp2f(p[i] - mnew); ls += p[i]; }
        lsum = lsum * corr + ls;
        acc[0] *= corr; acc[1] *= corr; acc[2] *= corr; acc[3] *= corr;
        m = mnew;

        // P bounce: write own 16 bf16 scores, read back in B-frag layout
#pragma unroll
        for (int tj = 0; tj < 4; ++tj) {
            uint2 u;
            u.x = pk2(p[tj * 4 + 0], p[tj * 4 + 1]);
            u.y = pk2(p[tj * 4 + 2], p[tj * 4 + 3]);
            *(uint2*)(pb + tj * 32 + pw_off) = u;
        }
        asm volatile("s_waitcnt lgkmcnt(0)" ::: "memory");
        __builtin_amdgcn_sched_barrier(0);

        // PV (swapped): acc = mfma(A=V^T-frag, B=P^T-frag, acc) -> lane holds O'[d][q]
        {
            uint4 pu0 = *(const uint4*)(pb + pr_off0);
            uint4 vu0 = *(const uint4*)(vb + va_off0);
            acc = __builtin_amdgcn_mfma_f32_16x16x32_bf16(
                __builtin_bit_cast(bf16x8, vu0), __builtin_bit_cast(bf16x8, pu0), acc, 0, 0, 0);
            uint4 pu1 = *(const uint4*)(pb + pr_off1);
            uint4 vu1 = *(const uint4*)(vb + va_off1);
            acc = __builtin_amdgcn_mfma_f32_16x16x32_bf16(
                __builtin_bit_cast(bf16x8, vu1), __builtin_bit_cast(bf16x8, pu1), acc, 0, 0, 0);
        }
        cur ^= 1;
    }

    lsum += __shfl_xor(lsum, 16);
    lsum += __shfl_xor(lsum, 32);
    float rl = 1.f / lsum;
#pragma unroll
    for (int i = 0; i < 4; ++i)
        xh[(size_t)(4 * gq + i) * NTOK + qb0 + q] = acc[i] * rl;
}

// ---------------------------------------------------------------- K3: rs1 = va + mlp1(xattn); rs2 = rs1 + mlp2(rs1)
__global__ __launch_bounds__(256) void k3_res_mlp(
    const float* __restrict__ xa, const float* __restrict__ va,
    const float* __restrict__ w1a, const float* __restrict__ b1a,
    const float* __restrict__ w2ta, const float* __restrict__ b2a,
    const float* __restrict__ w1b, const float* __restrict__ b1b,
    const float* __restrict__ w2tb, const float* __restrict__ b2b,
    float* __restrict__ outp)
{
    int t = threadIdx.x;
    int lane = t & 63, wave = t >> 6;
    int sub = lane >> 4, tl = lane & 15;
    int tok = blockIdx.x * 64 + wave * 16 + tl;
    int b = tok >> 12, n = tok & 4095;
    const float* xp = xa + (size_t)b * (64 * NTOK) + n;
    const float* vp = va + (size_t)b * (64 * NTOK) + n;
    float x[64];
#pragma unroll
    for (int c = 0; c < 64; ++c) x[c] = xp[(size_t)c * NTOK];

    float acc[64];
    mlp_partial(x, acc, w1a, b1a, w2ta, sub);
#pragma unroll
    for (int c = 0; c < 64; ++c) x[c] = vp[(size_t)c * NTOK] + acc[c] + b2a[c];

    mlp_partial(x, acc, w1b, b1b, w2tb, sub);

    if (sub == 0) {
        float* op = outp + (size_t)b * (64 * NTOK) + n;
#pragma unroll
        for (int o = 0; o < 64; ++o) op[(size_t)o * NTOK] = x[o] + acc[o] + b2b[o];
    }
}

// ----------------------------------------------------------------
extern "C" void kernel_launch(void* const* d_in, const int* in_sizes, int n_in,
                              void* d_out, int out_size, void* d_ws, size_t ws_size,
                              hipStream_t stream)
{
    (void)in_sizes; (void)n_in; (void)out_size; (void)ws_size;
    const float* q = (const float*)d_in[0];
    const float* k = (const float*)d_in[1];
    const float* v = (const float*)d_in[2];
    const float* q_ln_g = (const float*)d_in[3];
    const float* q_ln_b = (const float*)d_in[4];
    const float* q_w1 = (const float*)d_in[5];
    const float* q_b1 = (const float*)d_in[6];
    const float* q_w2 = (const float*)d_in[7];
    const float* q_b2 = (const float*)d_in[8];
    const float* k_ln_g = (const float*)d_in[9];
    const float* k_ln_b = (const float*)d_in[10];
    const float* k_w1 = (const float*)d_in[11];
    const float* k_b1 = (const float*)d_in[12];
    const float* k_w2 = (const float*)d_in[13];
    const float* k_b2 = (const float*)d_in[14];
    const float* v_ln_g = (const float*)d_in[15];
    const float* v_ln_b = (const float*)d_in[16];
    const float* v_w1 = (const float*)d_in[17];
    const float* v_b1 = (const float*)d_in[18];
    const float* v_w2 = (const float*)d_in[19];
    const float* v_b2 = (const float*)d_in[20];
    const float* m1_w1 = (const float*)d_in[21];
    const float* m1_b1 = (const float*)d_in[22];
    const float* m1_w2 = (const float*)d_in[23];
    const float* m1_b2 = (const float*)d_in[24];
    const float* m2_w1 = (const float*)d_in[25];
    const float* m2_b1 = (const float*)d_in[26];
    const float* m2_w2 = (const float*)d_in[27];
    const float* m2_b2 = (const float*)d_in[28];

    float* ws  = (float*)d_ws;
    float* w2t = ws + OFF_W2T;
    float* va  = ws + OFF_VA;
    float* xa  = ws + OFF_XA;
    u16t* qbf  = (u16t*)(ws + OFF_QBF);
    u16t* kbf  = (u16t*)(ws + OFF_KBF);
    u16t* vtb  = (u16t*)(ws + OFF_VTB);
    float* out = (float*)d_out;

    k0_transpose_w2<<<5, 256, 0, stream>>>(q_w2, k_w2, v_w2, m1_w2, m2_w2, w2t);

    const float QSCALE = 0.25f * 1.44269504089f;   // 1/sqrt(16) * log2(e), folded into Q
    K1Args aq = { q, q_ln_g, q_ln_b, q_w1, q_b1, w2t + 0 * 8192, q_b2, nullptr, qbf, 0, QSCALE };
    K1Args ak = { k, k_ln_g, k_ln_b, k_w1, k_b1, w2t + 1 * 8192, k_b2, nullptr, kbf, 0, 1.0f };
    K1Args av = { v, v_ln_g, v_ln_b, v_w1, v_b1, w2t + 2 * 8192, v_b2, va, vtb, 1, 1.0f };
    k1_ln_mlp<<<dim3(128, 3), 256, 0, stream>>>(aq, ak, av);

    k2_attn<<<dim3(64, 8), 256, 0, stream>>>(qbf, kbf, vtb, xa);

    k3_res_mlp<<<128, 256, 0, stream>>>(xa, va, m1_w1, m1_b1, w2t + 3 * 8192, m1_b2,
                                        m2_w1, m2_b1, w2t + 4 * 8192, m2_b2, out);
}

// Round 11
// 238.644 us; speedup vs baseline: 2.8120x; 1.7627x over previous
//
#include <hip/hip_runtime.h>

#define NTOK 4096     // H*W
#define NEGS 0.01f
#define EPSV 1e-5f

typedef unsigned short u16t;
typedef unsigned int u32t;

// workspace layout in float units
#define OFF_WP  0                        // 5 * 16384 packed weights (w1p 8192 + w2p 8192)
#define OFF_VA  81920                    // fp32 [B,C,N]
#define OFF_XA  (OFF_VA + 524288)        // fp32 [B,C,N]
#define OFF_QBF (OFF_XA + 524288)        // u16 [bh][n][16] (scaled)
#define OFF_KBF (OFF_QBF + 262144)       // u16 [bh][n][16]
#define OFF_VTB (OFF_KBF + 262144)       // u16 [b][c][n]

typedef __attribute__((address_space(1))) const void GV;
typedef __attribute__((address_space(3))) void LV;
using bf16x8 = __attribute__((ext_vector_type(8))) short;
using f32x4  = __attribute__((ext_vector_type(4))) float;

__device__ __forceinline__ void gll16(const void* g, void* l) {
    __builtin_amdgcn_global_load_lds((GV*)g, (LV*)l, 16, 0, 0);
}
// round-to-nearest-even f32 -> bf16 (raw bits)
__device__ __forceinline__ u32t bf16r(float x) {
    u32t u = __builtin_bit_cast(u32t, x);
    return (u + 0x7fffu + ((u >> 16) & 1u)) >> 16;
}
__device__ __forceinline__ u32t pk2(float a, float b) {
    return bf16r(a) | (bf16r(b) << 16);
}

// ---------------------------------------------------------------- K0: pack 5 MLP weight pairs for lane-coalesced reads
// w1p[cc*128 + j] (float4) = w1[j][4cc..4cc+3]   (w1: [128][64])
// w2p[jj*64 + c]  (float4) = w2[c][4jj..4jj+3]   (w2: [64][128])
struct PackArgs { const float* w1[5]; const float* w2[5]; };

__global__ __launch_bounds__(256) void k0_pack(PackArgs pa, float* __restrict__ wp)
{
    int m = blockIdx.x, t = threadIdx.x;
    const float* w1 = pa.w1[m];
    const float* w2 = pa.w2[m];
    float* d1 = wp + m * 16384;
    float* d2 = d1 + 8192;
    for (int e = t; e < 8192; e += 256) {
        int i = e & 3, j = (e >> 2) & 127, cc = e >> 9;
        d1[e] = w1[j * 64 + cc * 4 + i];
    }
    for (int e = t; e < 8192; e += 256) {
        int i = e & 3, c = (e >> 2) & 63, jj = e >> 8;
        d2[e] = w2[c * 128 + jj * 4 + i];
    }
}

// ---------------------------------------------------------------- shared wave-level MLP (4 tokens/wave, lane=channel)
// xs: [16][68] token-major activations; ht: [16][136] hidden scratch.
// Lane l computes h[l], h[l+64] (phase1) and y[l] (phase2) for 4 tokens.
__device__ __forceinline__ void wave_mlp(const float (*xs)[68], float (*ht)[136],
                                         const float* __restrict__ w1p,
                                         const float* __restrict__ b1,
                                         const float* __restrict__ w2p,
                                         int tb, int l, float* __restrict__ y)
{
    const float4* W1 = (const float4*)w1p;
    float h0[4] = {0.f, 0.f, 0.f, 0.f}, h1[4] = {0.f, 0.f, 0.f, 0.f};
#pragma unroll 4
    for (int cc = 0; cc < 16; ++cc) {
        float4 wA = W1[cc * 128 + l];
        float4 wB = W1[cc * 128 + 64 + l];
#pragma unroll
        for (int k = 0; k < 4; ++k) {
            float4 xv = *(const float4*)&xs[tb + k][cc * 4];
            h0[k] += xv.x * wA.x + xv.y * wA.y + xv.z * wA.z + xv.w * wA.w;
            h1[k] += xv.x * wB.x + xv.y * wB.y + xv.z * wB.z + xv.w * wB.w;
        }
    }
    float bA = b1[l], bB = b1[l + 64];
#pragma unroll
    for (int k = 0; k < 4; ++k) {
        float v0 = h0[k] + bA; v0 = v0 > 0.f ? v0 : NEGS * v0;
        float v1 = h1[k] + bB; v1 = v1 > 0.f ? v1 : NEGS * v1;
        ht[tb + k][l] = v0;
        ht[tb + k][64 + l] = v1;
    }
    __syncthreads();
    const float4* W2 = (const float4*)w2p;
    float ya[4] = {0.f, 0.f, 0.f, 0.f};
#pragma unroll 4
    for (int jj = 0; jj < 32; ++jj) {
        float4 wv = W2[jj * 64 + l];
#pragma unroll
        for (int k = 0; k < 4; ++k) {
            float4 hv = *(const float4*)&ht[tb + k][jj * 4];
            ya[k] += hv.x * wv.x + hv.y * wv.y + hv.z * wv.z + hv.w * wv.w;
        }
    }
#pragma unroll
    for (int k = 0; k < 4; ++k) y[k] = ya[k];
}

// ---------------------------------------------------------------- K1: LayerNorm + MLP, emits attention-ready bf16 layouts
struct K1Args {
    const float *x, *g, *b, *w1p, *b1, *w2p, *b2;
    float* ofp;      // fp32 [B,C,N] (v only)
    u16t* obf;       // bf16 out
    int mode;        // 0: obf=[bh][n][16] rows; 1: ofp fp32 + obf=[b][c][n]
    float scale;     // folded into bf16 values
};

__global__ __launch_bounds__(256) void k1_ln_mlp(K1Args a0, K1Args a1, K1Args a2)
{
    const K1Args& a = blockIdx.y == 0 ? a0 : blockIdx.y == 1 ? a1 : a2;
    __shared__ float xs[16][68];
    __shared__ float ht[16][136];
    __shared__ float ps[2][16][16];
    __shared__ float lnp[2][16];
    int t = threadIdx.x;
    int n0 = blockIdx.x * 16;
    int b = n0 >> 12, n = n0 & 4095;
    const float* xg = a.x + (size_t)b * (64 * NTOK) + n;

    {   // stage + transpose x tile [64 c][16 n] -> xs[tok][c]
        int c = t >> 2, q4 = t & 3;
        float4 v = *(const float4*)(xg + (size_t)c * NTOK + q4 * 4);
        xs[q4 * 4 + 0][c] = v.x; xs[q4 * 4 + 1][c] = v.y;
        xs[q4 * 4 + 2][c] = v.z; xs[q4 * 4 + 3][c] = v.w;
    }
    __syncthreads();
    {   // LN stats: partial sums over 4 channels per thread
        int tok = t & 15, part = t >> 4;
        float s = 0.f, ss = 0.f;
#pragma unroll
        for (int i = 0; i < 4; ++i) {
            float xv = xs[tok][part * 4 + i];
            s += xv; ss += xv * xv;
        }
        ps[0][part][tok] = s; ps[1][part][tok] = ss;
    }
    __syncthreads();
    if (t < 16) {
        float s = 0.f, ss = 0.f;
#pragma unroll
        for (int p = 0; p < 16; ++p) { s += ps[0][p][t]; ss += ps[1][p][t]; }
        float mean = s * (1.f / 64.f);
        float var = ss * (1.f / 64.f) - mean * mean;
        lnp[0][t] = mean;
        lnp[1][t] = rsqrtf(var + EPSV);
    }
    __syncthreads();
    {   // normalize in place
        int tok = t & 15, part = t >> 4;
        float mean = lnp[0][tok], rstd = lnp[1][tok];
#pragma unroll
        for (int i = 0; i < 4; ++i) {
            int c = part * 4 + i;
            xs[tok][c] = (xs[tok][c] - mean) * rstd * a.g[c] + a.b[c];
        }
    }
    __syncthreads();

    int w = t >> 6, l = t & 63, tb = w * 4;
    float y[4];
    wave_mlp(xs, ht, a.w1p, a.b1, a.w2p, tb, l, y);
    float b2v = a.b2[l];
    __syncthreads();                     // xs dead (phase1 done) -> reuse as yt
#pragma unroll
    for (int k = 0; k < 4; ++k) xs[tb + k][l] = y[k] + b2v;
    __syncthreads();

    if (a.mode == 0) {
        // bf16 rows [bh][n][16], scaled
        int tok = t & 15, p = t >> 4, hh = p >> 2, pr = p & 3;
        float ya = xs[tok][hh * 16 + 4 * pr + 0] * a.scale;
        float yb = xs[tok][hh * 16 + 4 * pr + 1] * a.scale;
        float yc = xs[tok][hh * 16 + 4 * pr + 2] * a.scale;
        float yd = xs[tok][hh * 16 + 4 * pr + 3] * a.scale;
        uint2 u; u.x = pk2(ya, yb); u.y = pk2(yc, yd);
        u16t* base = a.obf + (((size_t)b * 4 + hh) * NTOK + n + tok) * 16 + 4 * pr;
        *(uint2*)base = u;
    } else {
        int c = t >> 2, q4 = t & 3;
        float4 v = { xs[q4 * 4 + 0][c], xs[q4 * 4 + 1][c],
                     xs[q4 * 4 + 2][c], xs[q4 * 4 + 3][c] };
        *(float4*)(a.ofp + (size_t)b * (64 * NTOK) + (size_t)c * NTOK + n + q4 * 4) = v;
        uint2 u; u.x = pk2(v.x, v.y); u.y = pk2(v.z, v.w);
        *(uint2*)(a.obf + (size_t)b * (64 * NTOK) + (size_t)c * NTOK + n + q4 * 4) = u;
    }
}

// ---------------------------------------------------------------- K2: MFMA flash attention (unchanged, verified r9)
__global__ __launch_bounds__(256) void k2_attn(
    const u16t* __restrict__ qbf, const u16t* __restrict__ kbf,
    const u16t* __restrict__ vtb, float* __restrict__ xa)
{
    __shared__ __align__(16) char sm[8192 + 4 * 2304];
    int t = threadIdx.x;
    int l = t & 63, w = t >> 6;
    int q = l & 15, gq = l >> 4;
    int bh = blockIdx.y;
    int b = bh >> 2, h = bh & 3;
    int qb0 = blockIdx.x * 64 + w * 16;

    const u16t* qhead = qbf + (size_t)bh * NTOK * 16;
    const u16t* khead = kbf + (size_t)bh * NTOK * 16;
    const char* vhead = (const char*)(vtb + ((size_t)b * 64 + h * 16) * NTOK);
    float* xh = xa + ((size_t)b * 64 + h * 16) * NTOK;

    bf16x8 qf = {};
    if (l < 32) {
        uint4 u = *(const uint4*)(qhead + ((size_t)(qb0 + q)) * 16 + gq * 8);
        qf = __builtin_bit_cast(bf16x8, u);
    }

    const char* gsrc;
    int gstep;
    char* ldst;
    if (w < 2) {
        int s = w * 64 + l;
        int j = s >> 1, half = s & 1;
        int xh2 = half ^ ((j >> 2) & 1);
        gsrc = (const char*)khead + j * 32 + xh2 * 16;
        gstep = 2048;
        ldst = sm + w * 1024;
    } else {
        int s = (w - 2) * 64 + l;
        int d = s >> 3, su = s & 7;
        gsrc = vhead + d * 8192 + ((su * 16) ^ ((d & 7) << 4));
        gstep = 128;
        ldst = sm + 2048 + (w - 2) * 1024;
    }
    char* pb = sm + 8192 + w * 2304;

    int ka_off = q * 32 + (((gq & 1) ^ ((l >> 2) & 1)) << 4);
    int va_off0 = q * 128 + (((gq << 4) + 0) ^ ((q & 7) << 4));
    int va_off1 = q * 128 + (((gq << 4) + 64) ^ ((q & 7) << 4));
    int pw_off = q * 144 + (gq << 3);
    int pr_off0 = q * 144 + (gq << 4);
    int pr_off1 = q * 144 + 64 + (gq << 4);

    f32x4 acc = {0.f, 0.f, 0.f, 0.f};
    float m = -1e30f, lsum = 0.f;

    gll16(gsrc, ldst);

    int cur = 0;
#pragma unroll 1
    for (int it = 0; it < 64; ++it) {
        asm volatile("s_waitcnt vmcnt(0)" ::: "memory");
        __builtin_amdgcn_s_barrier();
        asm volatile("" ::: "memory");
        if (it < 63) gll16(gsrc + (it + 1) * gstep, ldst + ((cur ^ 1) << 12));
        const char* kb = sm + (cur << 12);
        const char* vb = kb + 2048;

        f32x4 z = {0.f, 0.f, 0.f, 0.f};
        f32x4 sf0, sf1, sf2, sf3;
        {
            bf16x8 k0 = {}, k1 = {}, k2v = {}, k3v = {};
            if (l < 32) {
                k0  = __builtin_bit_cast(bf16x8, *(const uint4*)(kb + 0 * 512 + ka_off));
                k1  = __builtin_bit_cast(bf16x8, *(const uint4*)(kb + 1 * 512 + ka_off));
                k2v = __builtin_bit_cast(bf16x8, *(const uint4*)(kb + 2 * 512 + ka_off));
                k3v = __builtin_bit_cast(bf16x8, *(const uint4*)(kb + 3 * 512 + ka_off));
            }
            sf0 = __builtin_amdgcn_mfma_f32_16x16x32_bf16(k0,  qf, z, 0, 0, 0);
            sf1 = __builtin_amdgcn_mfma_f32_16x16x32_bf16(k1,  qf, z, 0, 0, 0);
            sf2 = __builtin_amdgcn_mfma_f32_16x16x32_bf16(k2v, qf, z, 0, 0, 0);
            sf3 = __builtin_amdgcn_mfma_f32_16x16x32_bf16(k3v, qf, z, 0, 0, 0);
        }
        float p[16];
#pragma unroll
        for (int i = 0; i < 4; ++i) {
            p[i] = sf0[i]; p[4 + i] = sf1[i]; p[8 + i] = sf2[i]; p[12 + i] = sf3[i];
        }
        float mx = p[0];
#pragma unroll
        for (int i = 1; i < 16; ++i) mx = fmaxf(mx, p[i]);
        mx = fmaxf(mx, __shfl_xor(mx, 16));
        mx = fmaxf(mx, __shfl_xor(mx, 32));
        float mnew = fmaxf(m, mx);
        float corr = exp2f(m - mnew);
        float ls = 0.f;
#pragma unroll
        for (int i = 0; i < 16; ++i) { p[i] = exp2f(p[i] - mnew); ls += p[i]; }
        lsum = lsum * corr + ls;
        acc[0] *= corr; acc[1] *= corr; acc[2] *= corr; acc[3] *= corr;
        m = mnew;

#pragma unroll
        for (int tj = 0; tj < 4; ++tj) {
            uint2 u;
            u.x = pk2(p[tj * 4 + 0], p[tj * 4 + 1]);
            u.y = pk2(p[tj * 4 + 2], p[tj * 4 + 3]);
            *(uint2*)(pb + tj * 32 + pw_off) = u;
        }
        asm volatile("s_waitcnt lgkmcnt(0)" ::: "memory");
        __builtin_amdgcn_sched_barrier(0);

        {
            uint4 pu0 = *(const uint4*)(pb + pr_off0);
            uint4 vu0 = *(const uint4*)(vb + va_off0);
            acc = __builtin_amdgcn_mfma_f32_16x16x32_bf16(
                __builtin_bit_cast(bf16x8, vu0), __builtin_bit_cast(bf16x8, pu0), acc, 0, 0, 0);
            uint4 pu1 = *(const uint4*)(pb + pr_off1);
            uint4 vu1 = *(const uint4*)(vb + va_off1);
            acc = __builtin_amdgcn_mfma_f32_16x16x32_bf16(
                __builtin_bit_cast(bf16x8, vu1), __builtin_bit_cast(bf16x8, pu1), acc, 0, 0, 0);
        }
        cur ^= 1;
    }

    lsum += __shfl_xor(lsum, 16);
    lsum += __shfl_xor(lsum, 32);
    float rl = 1.f / lsum;
#pragma unroll
    for (int i = 0; i < 4; ++i)
        xh[(size_t)(4 * gq + i) * NTOK + qb0 + q] = acc[i] * rl;
}

// ---------------------------------------------------------------- K3: rs1 = va + mlp1(xattn); rs2 = rs1 + mlp2(rs1)
__global__ __launch_bounds__(256) void k3_res_mlp(
    const float* __restrict__ xa, const float* __restrict__ va,
    const float* __restrict__ w1pa, const float* __restrict__ b1a,
    const float* __restrict__ w2pa, const float* __restrict__ b2a,
    const float* __restrict__ w1pb, const float* __restrict__ b1b,
    const float* __restrict__ w2pb, const float* __restrict__ b2b,
    float* __restrict__ outp)
{
    __shared__ float xs[16][68];
    __shared__ float vat[16][68];
    __shared__ float ht[16][136];
    int t = threadIdx.x;
    int n0 = blockIdx.x * 16;
    int b = n0 >> 12, n = n0 & 4095;
    const float* xg = xa + (size_t)b * (64 * NTOK) + n;
    const float* vg = va + (size_t)b * (64 * NTOK) + n;

    {   // stage + transpose both tiles
        int c = t >> 2, q4 = t & 3;
        float4 v = *(const float4*)(xg + (size_t)c * NTOK + q4 * 4);
        xs[q4 * 4 + 0][c] = v.x; xs[q4 * 4 + 1][c] = v.y;
        xs[q4 * 4 + 2][c] = v.z; xs[q4 * 4 + 3][c] = v.w;
        float4 v2 = *(const float4*)(vg + (size_t)c * NTOK + q4 * 4);
        vat[q4 * 4 + 0][c] = v2.x; vat[q4 * 4 + 1][c] = v2.y;
        vat[q4 * 4 + 2][c] = v2.z; vat[q4 * 4 + 3][c] = v2.w;
    }
    __syncthreads();

    int w = t >> 6, l = t & 63, tb = w * 4;
    float y[4];
    wave_mlp(xs, ht, w1pa, b1a, w2pa, tb, l, y);
    float b2av = b2a[l];
    float r[4];
    __syncthreads();                 // all phase-2 ht reads done before rewrite
#pragma unroll
    for (int k = 0; k < 4; ++k) {
        r[k] = vat[tb + k][l] + y[k] + b2av;   // rs1
        xs[tb + k][l] = r[k];                  // mlp2 input
    }
    __syncthreads();

    wave_mlp(xs, ht, w1pb, b1b, w2pb, tb, l, y);
    float b2bv = b2b[l];
    __syncthreads();                 // xs dead -> reuse as yt
#pragma unroll
    for (int k = 0; k < 4; ++k) xs[tb + k][l] = r[k] + y[k] + b2bv;
    __syncthreads();

    {   // coalesced writeout [b][c][n]
        int c = t >> 2, q4 = t & 3;
        float4 v = { xs[q4 * 4 + 0][c], xs[q4 * 4 + 1][c],
                     xs[q4 * 4 + 2][c], xs[q4 * 4 + 3][c] };
        *(float4*)(outp + (size_t)b * (64 * NTOK) + (size_t)c * NTOK + n + q4 * 4) = v;
    }
}

// ----------------------------------------------------------------
extern "C" void kernel_launch(void* const* d_in, const int* in_sizes, int n_in,
                              void* d_out, int out_size, void* d_ws, size_t ws_size,
                              hipStream_t stream)
{
    (void)in_sizes; (void)n_in; (void)out_size; (void)ws_size;
    const float* q = (const float*)d_in[0];
    const float* k = (const float*)d_in[1];
    const float* v = (const float*)d_in[2];
    const float* q_ln_g = (const float*)d_in[3];
    const float* q_ln_b = (const float*)d_in[4];
    const float* q_w1 = (const float*)d_in[5];
    const float* q_b1 = (const float*)d_in[6];
    const float* q_w2 = (const float*)d_in[7];
    const float* q_b2 = (const float*)d_in[8];
    const float* k_ln_g = (const float*)d_in[9];
    const float* k_ln_b = (const float*)d_in[10];
    const float* k_w1 = (const float*)d_in[11];
    const float* k_b1 = (const float*)d_in[12];
    const float* k_w2 = (const float*)d_in[13];
    const float* k_b2 = (const float*)d_in[14];
    const float* v_ln_g = (const float*)d_in[15];
    const float* v_ln_b = (const float*)d_in[16];
    const float* v_w1 = (const float*)d_in[17];
    const float* v_b1 = (const float*)d_in[18];
    const float* v_w2 = (const float*)d_in[19];
    const float* v_b2 = (const float*)d_in[20];
    const float* m1_w1 = (const float*)d_in[21];
    const float* m1_b1 = (const float*)d_in[22];
    const float* m1_w2 = (const float*)d_in[23];
    const float* m1_b2 = (const float*)d_in[24];
    const float* m2_w1 = (const float*)d_in[25];
    const float* m2_b1 = (const float*)d_in[26];
    const float* m2_w2 = (const float*)d_in[27];
    const float* m2_b2 = (const float*)d_in[28];

    float* ws  = (float*)d_ws;
    float* wp  = ws + OFF_WP;
    float* va  = ws + OFF_VA;
    float* xa  = ws + OFF_XA;
    u16t* qbf  = (u16t*)(ws + OFF_QBF);
    u16t* kbf  = (u16t*)(ws + OFF_KBF);
    u16t* vtb  = (u16t*)(ws + OFF_VTB);
    float* out = (float*)d_out;

    PackArgs pa;
    pa.w1[0] = q_w1;  pa.w2[0] = q_w2;
    pa.w1[1] = k_w1;  pa.w2[1] = k_w2;
    pa.w1[2] = v_w1;  pa.w2[2] = v_w2;
    pa.w1[3] = m1_w1; pa.w2[3] = m1_w2;
    pa.w1[4] = m2_w1; pa.w2[4] = m2_w2;
    k0_pack<<<5, 256, 0, stream>>>(pa, wp);

    const float QSCALE = 0.25f * 1.44269504089f;   // 1/sqrt(16) * log2(e), folded into Q
    K1Args aq = { q, q_ln_g, q_ln_b, wp + 0 * 16384, q_b1, wp + 0 * 16384 + 8192, q_b2,
                  nullptr, qbf, 0, QSCALE };
    K1Args ak = { k, k_ln_g, k_ln_b, wp + 1 * 16384, k_b1, wp + 1 * 16384 + 8192, k_b2,
                  nullptr, kbf, 0, 1.0f };
    K1Args av = { v, v_ln_g, v_ln_b, wp + 2 * 16384, v_b1, wp + 2 * 16384 + 8192, v_b2,
                  va, vtb, 1, 1.0f };
    k1_ln_mlp<<<dim3(512, 3), 256, 0, stream>>>(aq, ak, av);

    k2_attn<<<dim3(64, 8), 256, 0, stream>>>(qbf, kbf, vtb, xa);

    k3_res_mlp<<<512, 256, 0, stream>>>(xa, va,
                                        wp + 3 * 16384, m1_b1, wp + 3 * 16384 + 8192, m1_b2,
                                        wp + 4 * 16384, m2_b1, wp + 4 * 16384 + 8192, m2_b2,
                                        out);
}

// Round 12
// 228.424 us; speedup vs baseline: 2.9379x; 1.0447x over previous
//
#include <hip/hip_runtime.h>

#define NTOK 4096     // H*W
#define NEGS 0.01f
#define EPSV 1e-5f

typedef unsigned short u16t;
typedef unsigned int u32t;

// workspace layout in float units
#define OFF_WP  0                        // 5 * 16384 packed weights (w1p 8192 + w2p 8192)
#define OFF_VA  81920                    // fp32 [B,C,N]
#define OFF_XA  (OFF_VA + 524288)        // fp32 [B,C,N]
#define OFF_QBF (OFF_XA + 524288)        // u16 [bh][n][16] (scaled)
#define OFF_KBF (OFF_QBF + 262144)       // u16 [bh][n][16]
#define OFF_VTB (OFF_KBF + 262144)       // u16 [b][c][n]

typedef __attribute__((address_space(1))) const void GV;
typedef __attribute__((address_space(3))) void LV;
using bf16x8 = __attribute__((ext_vector_type(8))) short;
using f32x4  = __attribute__((ext_vector_type(4))) float;

__device__ __forceinline__ void gll16(const void* g, void* l) {
    __builtin_amdgcn_global_load_lds((GV*)g, (LV*)l, 16, 0, 0);
}
// round-to-nearest-even f32 -> bf16 (raw bits) — cold paths only
__device__ __forceinline__ u32t bf16r(float x) {
    u32t u = __builtin_bit_cast(u32t, x);
    return (u + 0x7fffu + ((u >> 16) & 1u)) >> 16;
}
__device__ __forceinline__ u32t pk2(float a, float b) {
    return bf16r(a) | (bf16r(b) << 16);
}
// hot path: single-instruction packed RNE convert (lo=a, hi=b)
__device__ __forceinline__ u32t cvtpk(float a, float b) {
    u32t r;
    asm("v_cvt_pk_bf16_f32 %0, %1, %2" : "=v"(r) : "v"(a), "v"(b));
    return r;
}

// ---------------------------------------------------------------- K0: pack 5 MLP weight pairs for lane-coalesced reads
struct PackArgs { const float* w1[5]; const float* w2[5]; };

__global__ __launch_bounds__(256) void k0_pack(PackArgs pa, float* __restrict__ wp)
{
    int m = blockIdx.x, t = threadIdx.x;
    const float* w1 = pa.w1[m];
    const float* w2 = pa.w2[m];
    float* d1 = wp + m * 16384;
    float* d2 = d1 + 8192;
    for (int e = t; e < 8192; e += 256) {
        int i = e & 3, j = (e >> 2) & 127, cc = e >> 9;
        d1[e] = w1[j * 64 + cc * 4 + i];
    }
    for (int e = t; e < 8192; e += 256) {
        int i = e & 3, c = (e >> 2) & 63, jj = e >> 8;
        d2[e] = w2[c * 128 + jj * 4 + i];
    }
}

// ---------------------------------------------------------------- shared wave-level MLP (4 tokens/wave, lane=channel)
__device__ __forceinline__ void wave_mlp(const float (*xs)[68], float (*ht)[136],
                                         const float* __restrict__ w1p,
                                         const float* __restrict__ b1,
                                         const float* __restrict__ w2p,
                                         int tb, int l, float* __restrict__ y)
{
    const float4* W1 = (const float4*)w1p;
    float h0[4] = {0.f, 0.f, 0.f, 0.f}, h1[4] = {0.f, 0.f, 0.f, 0.f};
#pragma unroll 4
    for (int cc = 0; cc < 16; ++cc) {
        float4 wA = W1[cc * 128 + l];
        float4 wB = W1[cc * 128 + 64 + l];
#pragma unroll
        for (int k = 0; k < 4; ++k) {
            float4 xv = *(const float4*)&xs[tb + k][cc * 4];
            h0[k] += xv.x * wA.x + xv.y * wA.y + xv.z * wA.z + xv.w * wA.w;
            h1[k] += xv.x * wB.x + xv.y * wB.y + xv.z * wB.z + xv.w * wB.w;
        }
    }
    float bA = b1[l], bB = b1[l + 64];
#pragma unroll
    for (int k = 0; k < 4; ++k) {
        float v0 = h0[k] + bA; v0 = v0 > 0.f ? v0 : NEGS * v0;
        float v1 = h1[k] + bB; v1 = v1 > 0.f ? v1 : NEGS * v1;
        ht[tb + k][l] = v0;
        ht[tb + k][64 + l] = v1;
    }
    __syncthreads();
    const float4* W2 = (const float4*)w2p;
    float ya[4] = {0.f, 0.f, 0.f, 0.f};
#pragma unroll 4
    for (int jj = 0; jj < 32; ++jj) {
        float4 wv = W2[jj * 64 + l];
#pragma unroll
        for (int k = 0; k < 4; ++k) {
            float4 hv = *(const float4*)&ht[tb + k][jj * 4];
            ya[k] += hv.x * wv.x + hv.y * wv.y + hv.z * wv.z + hv.w * wv.w;
        }
    }
#pragma unroll
    for (int k = 0; k < 4; ++k) y[k] = ya[k];
}

// ---------------------------------------------------------------- K1: LayerNorm + MLP, emits attention-ready bf16 layouts
struct K1Args {
    const float *x, *g, *b, *w1p, *b1, *w2p, *b2;
    float* ofp;
    u16t* obf;
    int mode;
    float scale;
};

__global__ __launch_bounds__(256) void k1_ln_mlp(K1Args a0, K1Args a1, K1Args a2)
{
    const K1Args& a = blockIdx.y == 0 ? a0 : blockIdx.y == 1 ? a1 : a2;
    __shared__ float xs[16][68];
    __shared__ float ht[16][136];
    __shared__ float ps[2][16][16];
    __shared__ float lnp[2][16];
    int t = threadIdx.x;
    int n0 = blockIdx.x * 16;
    int b = n0 >> 12, n = n0 & 4095;
    const float* xg = a.x + (size_t)b * (64 * NTOK) + n;

    {
        int c = t >> 2, q4 = t & 3;
        float4 v = *(const float4*)(xg + (size_t)c * NTOK + q4 * 4);
        xs[q4 * 4 + 0][c] = v.x; xs[q4 * 4 + 1][c] = v.y;
        xs[q4 * 4 + 2][c] = v.z; xs[q4 * 4 + 3][c] = v.w;
    }
    __syncthreads();
    {
        int tok = t & 15, part = t >> 4;
        float s = 0.f, ss = 0.f;
#pragma unroll
        for (int i = 0; i < 4; ++i) {
            float xv = xs[tok][part * 4 + i];
            s += xv; ss += xv * xv;
        }
        ps[0][part][tok] = s; ps[1][part][tok] = ss;
    }
    __syncthreads();
    if (t < 16) {
        float s = 0.f, ss = 0.f;
#pragma unroll
        for (int p = 0; p < 16; ++p) { s += ps[0][p][t]; ss += ps[1][p][t]; }
        float mean = s * (1.f / 64.f);
        float var = ss * (1.f / 64.f) - mean * mean;
        lnp[0][t] = mean;
        lnp[1][t] = rsqrtf(var + EPSV);
    }
    __syncthreads();
    {
        int tok = t & 15, part = t >> 4;
        float mean = lnp[0][tok], rstd = lnp[1][tok];
#pragma unroll
        for (int i = 0; i < 4; ++i) {
            int c = part * 4 + i;
            xs[tok][c] = (xs[tok][c] - mean) * rstd * a.g[c] + a.b[c];
        }
    }
    __syncthreads();

    int w = t >> 6, l = t & 63, tb = w * 4;
    float y[4];
    wave_mlp(xs, ht, a.w1p, a.b1, a.w2p, tb, l, y);
    float b2v = a.b2[l];
    __syncthreads();
#pragma unroll
    for (int k = 0; k < 4; ++k) xs[tb + k][l] = y[k] + b2v;
    __syncthreads();

    if (a.mode == 0) {
        int tok = t & 15, p = t >> 4, hh = p >> 2, pr = p & 3;
        float ya = xs[tok][hh * 16 + 4 * pr + 0] * a.scale;
        float yb = xs[tok][hh * 16 + 4 * pr + 1] * a.scale;
        float yc = xs[tok][hh * 16 + 4 * pr + 2] * a.scale;
        float yd = xs[tok][hh * 16 + 4 * pr + 3] * a.scale;
        uint2 u; u.x = pk2(ya, yb); u.y = pk2(yc, yd);
        u16t* base = a.obf + (((size_t)b * 4 + hh) * NTOK + n + tok) * 16 + 4 * pr;
        *(uint2*)base = u;
    } else {
        int c = t >> 2, q4 = t & 3;
        float4 v = { xs[q4 * 4 + 0][c], xs[q4 * 4 + 1][c],
                     xs[q4 * 4 + 2][c], xs[q4 * 4 + 3][c] };
        *(float4*)(a.ofp + (size_t)b * (64 * NTOK) + (size_t)c * NTOK + n + q4 * 4) = v;
        uint2 u; u.x = pk2(v.x, v.y); u.y = pk2(v.z, v.w);
        *(uint2*)(a.obf + (size_t)b * (64 * NTOK) + (size_t)c * NTOK + n + q4 * 4) = u;
    }
}

// ---------------------------------------------------------------- K2: MFMA flash attention (r9-verified structure,
// softmax VALU diet: max3 tree + pairwise sum tree + v_cvt_pk_bf16_f32)
__global__ __launch_bounds__(256) void k2_attn(
    const u16t* __restrict__ qbf, const u16t* __restrict__ kbf,
    const u16t* __restrict__ vtb, float* __restrict__ xa)
{
    __shared__ __align__(16) char sm[8192 + 4 * 2304];
    int t = threadIdx.x;
    int l = t & 63, w = t >> 6;
    int q = l & 15, gq = l >> 4;
    int bh = blockIdx.y;
    int b = bh >> 2, h = bh & 3;
    int qb0 = blockIdx.x * 64 + w * 16;

    const u16t* qhead = qbf + (size_t)bh * NTOK * 16;
    const u16t* khead = kbf + (size_t)bh * NTOK * 16;
    const char* vhead = (const char*)(vtb + ((size_t)b * 64 + h * 16) * NTOK);
    float* xh = xa + ((size_t)b * 64 + h * 16) * NTOK;

    bf16x8 qf = {};
    if (l < 32) {
        uint4 u = *(const uint4*)(qhead + ((size_t)(qb0 + q)) * 16 + gq * 8);
        qf = __builtin_bit_cast(bf16x8, u);
    }

    const char* gsrc;
    int gstep;
    char* ldst;
    if (w < 2) {
        int s = w * 64 + l;
        int j = s >> 1, half = s & 1;
        int xh2 = half ^ ((j >> 2) & 1);
        gsrc = (const char*)khead + j * 32 + xh2 * 16;
        gstep = 2048;
        ldst = sm + w * 1024;
    } else {
        int s = (w - 2) * 64 + l;
        int d = s >> 3, su = s & 7;
        gsrc = vhead + d * 8192 + ((su * 16) ^ ((d & 7) << 4));
        gstep = 128;
        ldst = sm + 2048 + (w - 2) * 1024;
    }
    char* pb = sm + 8192 + w * 2304;

    int ka_off = q * 32 + (((gq & 1) ^ ((l >> 2) & 1)) << 4);
    int va_off0 = q * 128 + (((gq << 4) + 0) ^ ((q & 7) << 4));
    int va_off1 = q * 128 + (((gq << 4) + 64) ^ ((q & 7) << 4));
    int pw_off = q * 144 + (gq << 3);
    int pr_off0 = q * 144 + (gq << 4);
    int pr_off1 = q * 144 + 64 + (gq << 4);

    f32x4 acc = {0.f, 0.f, 0.f, 0.f};
    float m = -1e30f, lsum = 0.f;

    gll16(gsrc, ldst);

    int cur = 0;
#pragma unroll 1
    for (int it = 0; it < 64; ++it) {
        asm volatile("s_waitcnt vmcnt(0)" ::: "memory");
        __builtin_amdgcn_s_barrier();
        asm volatile("" ::: "memory");
        if (it < 63) gll16(gsrc + (it + 1) * gstep, ldst + ((cur ^ 1) << 12));
        const char* kb = sm + (cur << 12);
        const char* vb = kb + 2048;

        f32x4 z = {0.f, 0.f, 0.f, 0.f};
        f32x4 sf0, sf1, sf2, sf3;
        {
            bf16x8 k0 = {}, k1 = {}, k2v = {}, k3v = {};
            if (l < 32) {
                k0  = __builtin_bit_cast(bf16x8, *(const uint4*)(kb + 0 * 512 + ka_off));
                k1  = __builtin_bit_cast(bf16x8, *(const uint4*)(kb + 1 * 512 + ka_off));
                k2v = __builtin_bit_cast(bf16x8, *(const uint4*)(kb + 2 * 512 + ka_off));
                k3v = __builtin_bit_cast(bf16x8, *(const uint4*)(kb + 3 * 512 + ka_off));
            }
            sf0 = __builtin_amdgcn_mfma_f32_16x16x32_bf16(k0,  qf, z, 0, 0, 0);
            sf1 = __builtin_amdgcn_mfma_f32_16x16x32_bf16(k1,  qf, z, 0, 0, 0);
            sf2 = __builtin_amdgcn_mfma_f32_16x16x32_bf16(k2v, qf, z, 0, 0, 0);
            sf3 = __builtin_amdgcn_mfma_f32_16x16x32_bf16(k3v, qf, z, 0, 0, 0);
        }
        float p[16];
#pragma unroll
        for (int i = 0; i < 4; ++i) {
            p[i] = sf0[i]; p[4 + i] = sf1[i]; p[8 + i] = sf2[i]; p[12 + i] = sf3[i];
        }
        // max over 16 via max3-fusable tree (depth ~3)
        float ma = fmaxf(fmaxf(p[0], p[1]), p[2]);
        float mb = fmaxf(fmaxf(p[3], p[4]), p[5]);
        float mc = fmaxf(fmaxf(p[6], p[7]), p[8]);
        float md = fmaxf(fmaxf(p[9], p[10]), p[11]);
        float me = fmaxf(fmaxf(p[12], p[13]), p[14]);
        float mf2 = fmaxf(fmaxf(ma, mb), mc);
        float mg2 = fmaxf(fmaxf(md, me), p[15]);
        float mx = fmaxf(mf2, mg2);
        mx = fmaxf(mx, __shfl_xor(mx, 16));
        mx = fmaxf(mx, __shfl_xor(mx, 32));
        float mnew = fmaxf(m, mx);
        float corr = exp2f(m - mnew);
#pragma unroll
        for (int i = 0; i < 16; ++i) p[i] = exp2f(p[i] - mnew);
        // pairwise sum tree (depth 4 instead of serial 16)
        float s0 = (p[0] + p[1]) + (p[2] + p[3]);
        float s1 = (p[4] + p[5]) + (p[6] + p[7]);
        float s2 = (p[8] + p[9]) + (p[10] + p[11]);
        float s3 = (p[12] + p[13]) + (p[14] + p[15]);
        float ls = (s0 + s1) + (s2 + s3);
        lsum = lsum * corr + ls;
        acc[0] *= corr; acc[1] *= corr; acc[2] *= corr; acc[3] *= corr;
        m = mnew;

        // P bounce via packed cvt (1 instr / 2 values)
#pragma unroll
        for (int tj = 0; tj < 4; ++tj) {
            uint2 u;
            u.x = cvtpk(p[tj * 4 + 0], p[tj * 4 + 1]);
            u.y = cvtpk(p[tj * 4 + 2], p[tj * 4 + 3]);
            *(uint2*)(pb + tj * 32 + pw_off) = u;
        }
        asm volatile("s_waitcnt lgkmcnt(0)" ::: "memory");
        __builtin_amdgcn_sched_barrier(0);

        {
            uint4 pu0 = *(const uint4*)(pb + pr_off0);
            uint4 vu0 = *(const uint4*)(vb + va_off0);
            acc = __builtin_amdgcn_mfma_f32_16x16x32_bf16(
                __builtin_bit_cast(bf16x8, vu0), __builtin_bit_cast(bf16x8, pu0), acc, 0, 0, 0);
            uint4 pu1 = *(const uint4*)(pb + pr_off1);
            uint4 vu1 = *(const uint4*)(vb + va_off1);
            acc = __builtin_amdgcn_mfma_f32_16x16x32_bf16(
                __builtin_bit_cast(bf16x8, vu1), __builtin_bit_cast(bf16x8, pu1), acc, 0, 0, 0);
        }
        cur ^= 1;
    }

    lsum += __shfl_xor(lsum, 16);
    lsum += __shfl_xor(lsum, 32);
    float rl = 1.f / lsum;
#pragma unroll
    for (int i = 0; i < 4; ++i)
        xh[(size_t)(4 * gq + i) * NTOK + qb0 + q] = acc[i] * rl;
}

// ---------------------------------------------------------------- K3: rs1 = va + mlp1(xattn); rs2 = rs1 + mlp2(rs1)
__global__ __launch_bounds__(256) void k3_res_mlp(
    const float* __restrict__ xa, const float* __restrict__ va,
    const float* __restrict__ w1pa, const float* __restrict__ b1a,
    const float* __restrict__ w2pa, const float* __restrict__ b2a,
    const float* __restrict__ w1pb, const float* __restrict__ b1b,
    const float* __restrict__ w2pb, const float* __restrict__ b2b,
    float* __restrict__ outp)
{
    __shared__ float xs[16][68];
    __shared__ float vat[16][68];
    __shared__ float ht[16][136];
    int t = threadIdx.x;
    int n0 = blockIdx.x * 16;
    int b = n0 >> 12, n = n0 & 4095;
    const float* xg = xa + (size_t)b * (64 * NTOK) + n;
    const float* vg = va + (size_t)b * (64 * NTOK) + n;

    {
        int c = t >> 2, q4 = t & 3;
        float4 v = *(const float4*)(xg + (size_t)c * NTOK + q4 * 4);
        xs[q4 * 4 + 0][c] = v.x; xs[q4 * 4 + 1][c] = v.y;
        xs[q4 * 4 + 2][c] = v.z; xs[q4 * 4 + 3][c] = v.w;
        float4 v2 = *(const float4*)(vg + (size_t)c * NTOK + q4 * 4);
        vat[q4 * 4 + 0][c] = v2.x; vat[q4 * 4 + 1][c] = v2.y;
        vat[q4 * 4 + 2][c] = v2.z; vat[q4 * 4 + 3][c] = v2.w;
    }
    __syncthreads();

    int w = t >> 6, l = t & 63, tb = w * 4;
    float y[4];
    wave_mlp(xs, ht, w1pa, b1a, w2pa, tb, l, y);
    float b2av = b2a[l];
    float r[4];
    __syncthreads();
#pragma unroll
    for (int k = 0; k < 4; ++k) {
        r[k] = vat[tb + k][l] + y[k] + b2av;
        xs[tb + k][l] = r[k];
    }
    __syncthreads();

    wave_mlp(xs, ht, w1pb, b1b, w2pb, tb, l, y);
    float b2bv = b2b[l];
    __syncthreads();
#pragma unroll
    for (int k = 0; k < 4; ++k) xs[tb + k][l] = r[k] + y[k] + b2bv;
    __syncthreads();

    {
        int c = t >> 2, q4 = t & 3;
        float4 v = { xs[q4 * 4 + 0][c], xs[q4 * 4 + 1][c],
                     xs[q4 * 4 + 2][c], xs[q4 * 4 + 3][c] };
        *(float4*)(outp + (size_t)b * (64 * NTOK) + (size_t)c * NTOK + n + q4 * 4) = v;
    }
}

// ----------------------------------------------------------------
extern "C" void kernel_launch(void* const* d_in, const int* in_sizes, int n_in,
                              void* d_out, int out_size, void* d_ws, size_t ws_size,
                              hipStream_t stream)
{
    (void)in_sizes; (void)n_in; (void)out_size; (void)ws_size;
    const float* q = (const float*)d_in[0];
    const float* k = (const float*)d_in[1];
    const float* v = (const float*)d_in[2];
    const float* q_ln_g = (const float*)d_in[3];
    const float* q_ln_b = (const float*)d_in[4];
    const float* q_w1 = (const float*)d_in[5];
    const float* q_b1 = (const float*)d_in[6];
    const float* q_w2 = (const float*)d_in[7];
    const float* q_b2 = (const float*)d_in[8];
    const float* k_ln_g = (const float*)d_in[9];
    const float* k_ln_b = (const float*)d_in[10];
    const float* k_w1 = (const float*)d_in[11];
    const float* k_b1 = (const float*)d_in[12];
    const float* k_w2 = (const float*)d_in[13];
    const float* k_b2 = (const float*)d_in[14];
    const float* v_ln_g = (const float*)d_in[15];
    const float* v_ln_b = (const float*)d_in[16];
    const float* v_w1 = (const float*)d_in[17];
    const float* v_b1 = (const float*)d_in[18];
    const float* v_w2 = (const float*)d_in[19];
    const float* v_b2 = (const float*)d_in[20];
    const float* m1_w1 = (const float*)d_in[21];
    const float* m1_b1 = (const float*)d_in[22];
    const float* m1_w2 = (const float*)d_in[23];
    const float* m1_b2 = (const float*)d_in[24];
    const float* m2_w1 = (const float*)d_in[25];
    const float* m2_b1 = (const float*)d_in[26];
    const float* m2_w2 = (const float*)d_in[27];
    const float* m2_b2 = (const float*)d_in[28];

    float* ws  = (float*)d_ws;
    float* wp  = ws + OFF_WP;
    float* va  = ws + OFF_VA;
    float* xa  = ws + OFF_XA;
    u16t* qbf  = (u16t*)(ws + OFF_QBF);
    u16t* kbf  = (u16t*)(ws + OFF_KBF);
    u16t* vtb  = (u16t*)(ws + OFF_VTB);
    float* out = (float*)d_out;

    PackArgs pa;
    pa.w1[0] = q_w1;  pa.w2[0] = q_w2;
    pa.w1[1] = k_w1;  pa.w2[1] = k_w2;
    pa.w1[2] = v_w1;  pa.w2[2] = v_w2;
    pa.w1[3] = m1_w1; pa.w2[3] = m1_w2;
    pa.w1[4] = m2_w1; pa.w2[4] = m2_w2;
    k0_pack<<<5, 256, 0, stream>>>(pa, wp);

    const float QSCALE = 0.25f * 1.44269504089f;   // 1/sqrt(16) * log2(e), folded into Q
    K1Args aq = { q, q_ln_g, q_ln_b, wp + 0 * 16384, q_b1, wp + 0 * 16384 + 8192, q_b2,
                  nullptr, qbf, 0, QSCALE };
    K1Args ak = { k, k_ln_g, k_ln_b, wp + 1 * 16384, k_b1, wp + 1 * 16384 + 8192, k_b2,
                  nullptr, kbf, 0, 1.0f };
    K1Args av = { v, v_ln_g, v_ln_b, wp + 2 * 16384, v_b1, wp + 2 * 16384 + 8192, v_b2,
                  va, vtb, 1, 1.0f };
    k1_ln_mlp<<<dim3(512, 3), 256, 0, stream>>>(aq, ak, av);

    k2_attn<<<dim3(64, 8), 256, 0, stream>>>(qbf, kbf, vtb, xa);

    k3_res_mlp<<<512, 256, 0, stream>>>(xa, va,
                                        wp + 3 * 16384, m1_b1, wp + 3 * 16384 + 8192, m1_b2,
                                        wp + 4 * 16384, m2_b1, wp + 4 * 16384 + 8192, m2_b2,
                                        out);
}